// Round 2
// baseline (547.127 us; speedup 1.0000x reference)
//
#include <hip/hip_runtime.h>
#include <hip/hip_bf16.h>

typedef __attribute__((ext_vector_type(4))) float f32x4;
typedef __attribute__((ext_vector_type(8))) short s16x8;

#define NR 512      // rows of x / out
#define KD 512      // inner dim
#define CC 100000   // columns of weight / out
#define BN 32       // cols per wave (and per block; all 4 waves share the stripe)

static __device__ __forceinline__ unsigned short f2bf(float f) {
    union { float f; unsigned u; } v; v.f = f;
    unsigned r = v.u + 0x7FFFu + ((v.u >> 16) & 1u);  // round-to-nearest-even
    return (unsigned short)(r >> 16);
}

// Kernel 1: per-row L2 norm of x + convert x to bf16 (bit pattern in ushort)
__global__ __launch_bounds__(256) void prep_kernel(const float* __restrict__ x,
                                                   float* __restrict__ xn,
                                                   unsigned short* __restrict__ xb) {
    const int row = blockIdx.x;
    const int t = threadIdx.x;
    const float* xr = x + row * KD;
    float v0 = xr[t];
    float v1 = xr[t + 256];
    float ss = v0 * v0 + v1 * v1;
    #pragma unroll
    for (int off = 32; off > 0; off >>= 1) ss += __shfl_down(ss, off, 64);
    __shared__ float sred[4];
    if ((t & 63) == 0) sred[t >> 6] = ss;
    __syncthreads();
    if (t == 0) xn[row] = sqrtf(sred[0] + sred[1] + sred[2] + sred[3]);
    xb[row * KD + t]       = f2bf(v0);
    xb[row * KD + t + 256] = f2bf(v1);
}

// Kernel 2: barrier-free GEMM. Block = 4 independent waves sharing one 32-col
// stripe; wave wv computes rows [wv*128, wv*128+128) x 32 cols.
// B-fragments (B[k=quad*8+j][n=lane&15]) loaded DIRECTLY from global as
// stride-CC dword gathers (fp32), squared for the column norm, converted to
// bf16 in-register. No LDS, no __syncthreads in the hot loop.
__global__ __launch_bounds__(256, 3) void gemm_kernel(const float* __restrict__ w,
                                                      const unsigned short* __restrict__ xb,
                                                      const float* __restrict__ xn,
                                                      float* __restrict__ out) {
    const int t    = threadIdx.x;
    const int lane = t & 63;
    const int wv   = t >> 6;            // wave 0..3 -> row group
    const int c0   = blockIdx.x * BN;   // 3125 * 32 = 100000 exact
    const int n    = lane & 15;         // col-within-tile (A.m / B.n / C.col)
    const int q    = lane >> 4;         // k-quad (A.k/B.k = q*8+j; C.row = q*4+r)
    const int rowbase = wv * 128;

    f32x4 acc[8][2];
    #pragma unroll
    for (int i = 0; i < 8; ++i) {
        acc[i][0] = {0.f, 0.f, 0.f, 0.f};
        acc[i][1] = {0.f, 0.f, 0.f, 0.f};
    }

    // A pointers: row = rowbase + rt*16 + n, base k = q*8; advance 32/iter
    const unsigned short* ap[8];
    #pragma unroll
    for (int rt = 0; rt < 8; ++rt)
        ap[rt] = xb + (size_t)(rowbase + rt * 16 + n) * KD + q * 8;

    // B gather base: rows k = q*8+j (j=0..7), cols c0+n and c0+16+n
    const float* wp = w + (size_t)(q * 8) * CC + c0 + n;

    float bc0[8], bc1[8];               // current fp32 B values
    #pragma unroll
    for (int j = 0; j < 8; ++j) {
        const float* p = wp + (size_t)j * CC;
        bc0[j] = p[0];
        bc1[j] = p[16];
    }
    wp += (size_t)32 * CC;

    float ss0 = 0.f, ss1 = 0.f;         // per-lane partial column sumsq (fp32)

    #pragma unroll 1
    for (int it = 0; it < 16; ++it) {
        // prefetch next B chunk (independent of this iter's compute)
        float bn0[8], bn1[8];
        #pragma unroll
        for (int j = 0; j < 8; ++j) { bn0[j] = 0.f; bn1[j] = 0.f; }
        if (it < 15) {
            #pragma unroll
            for (int j = 0; j < 8; ++j) {
                const float* p = wp + (size_t)j * CC;
                bn0[j] = p[0];
                bn1[j] = p[16];
            }
        }

        // A fragments for this K-slice (L2-resident x_bf16)
        s16x8 af[8];
        #pragma unroll
        for (int rt = 0; rt < 8; ++rt)
            af[rt] = *(const s16x8*)(ap[rt] + it * 32);

        // column sumsq (fp32, pre-conversion) + pack B frags to bf16
        s16x8 bf0, bf1;
        #pragma unroll
        for (int j = 0; j < 8; ++j) {
            ss0 += bc0[j] * bc0[j];
            ss1 += bc1[j] * bc1[j];
            bf0[j] = (short)f2bf(bc0[j]);
            bf1[j] = (short)f2bf(bc1[j]);
        }

        #pragma unroll
        for (int rt = 0; rt < 8; ++rt) {
            acc[rt][0] = __builtin_amdgcn_mfma_f32_16x16x32_bf16(af[rt], bf0, acc[rt][0], 0, 0, 0);
            acc[rt][1] = __builtin_amdgcn_mfma_f32_16x16x32_bf16(af[rt], bf1, acc[rt][1], 0, 0, 0);
        }

        #pragma unroll
        for (int j = 0; j < 8; ++j) { bc0[j] = bn0[j]; bc1[j] = bn1[j]; }
        wp += (size_t)32 * CC;
    }

    // reduce column sumsq across the 4 k-quads (lanes n, n+16, n+32, n+48)
    ss0 += __shfl_xor(ss0, 16, 64);
    ss0 += __shfl_xor(ss0, 32, 64);
    ss1 += __shfl_xor(ss1, 16, 64);
    ss1 += __shfl_xor(ss1, 32, 64);
    const float inv0 = 1.0f / sqrtf(ss0);
    const float inv1 = 1.0f / sqrtf(ss1);

    // epilogue: C/D layout col = lane&15 (=n), row = q*4 + reg
    #pragma unroll
    for (int rt = 0; rt < 8; ++rt) {
        const int rbase = rowbase + rt * 16 + q * 4;
        const f32x4 xnv = *(const f32x4*)(xn + rbase);
        #pragma unroll
        for (int ct = 0; ct < 2; ++ct) {
            const float inv = ct ? inv1 : inv0;
            float* op = out + (size_t)rbase * CC + c0 + ct * 16 + n;
            #pragma unroll
            for (int r = 0; r < 4; ++r) {
                float cv = acc[rt][ct][r] * inv / xnv[r];
                cv = fminf(1.0f, fmaxf(-1.0f, cv));
                op[(size_t)r * CC] = cv * xnv[r];
            }
        }
    }
}

// Kernel 3: per-row target fixup (AngleLinear margin term), 512 rows
__global__ __launch_bounds__(512) void fixup_kernel(const int* __restrict__ target,
                                                    const float* __restrict__ xn,
                                                    float* __restrict__ out) {
    const int i = threadIdx.x;
    const int tg = target[i];
    const float xni = xn[i];
    float* p = out + (size_t)i * CC + tg;
    const float val = *p;
    float c = val / xni;
    c = fminf(1.0f, fmaxf(-1.0f, c));
    const float c2 = c * c;
    const float cosm = 8.0f * c2 * c2 - 8.0f * c2 + 1.0f;
    const float theta = acosf(c);
    const float kf = floorf(4.0f * theta / 3.141592653f);
    const float sign = (((int)kf) & 1) ? -1.0f : 1.0f;
    const float phi = sign * cosm - 2.0f * kf;
    const float lam = 1500.0f / 1.1f;  // max(5, 1500/(1+0.1*1))
    const float add = (phi - c) * xni / (1.0f + lam);
    *p = val + add;
}

extern "C" void kernel_launch(void* const* d_in, const int* in_sizes, int n_in,
                              void* d_out, int out_size, void* d_ws, size_t ws_size,
                              hipStream_t stream) {
    const float* x      = (const float*)d_in[0];
    const int*   target = (const int*)d_in[1];
    const float* w      = (const float*)d_in[2];
    float* out = (float*)d_out;

    float* xn = (float*)d_ws;                                        // 512 f32
    unsigned short* xb = (unsigned short*)((char*)d_ws + 2048);      // 512x512 bf16

    prep_kernel<<<NR, 256, 0, stream>>>(x, xn, xb);
    gemm_kernel<<<CC / BN, 256, 0, stream>>>(w, xb, xn, out);
    fixup_kernel<<<1, 512, 0, stream>>>(target, xn, out);
}